// Round 1
// baseline (1477.190 us; speedup 1.0000x reference)
//
#include <hip/hip_runtime.h>
#include <hip/hip_bf16.h>
#include <stdint.h>

#define GCAP 64          // max stored in-degree (Poisson(16): P(>=64) ~ 1e-20)
#define MPAD 50048       // 391 * 128

typedef __attribute__((ext_vector_type(8))) short short8;
typedef __attribute__((ext_vector_type(4))) short short4v;
typedef __attribute__((ext_vector_type(4))) float f32x4;

__device__ __forceinline__ unsigned short f2b(float f) {
  unsigned u = __float_as_uint(f);
  u += 0x7FFF + ((u >> 16) & 1);            // round-to-nearest-even
  return (unsigned short)(u >> 16);
}
__device__ __forceinline__ float b2f(unsigned short s) {
  return __uint_as_float(((unsigned)s) << 16);
}
__device__ __forceinline__ void load_lds16(const void* g, void* l) {
  __builtin_amdgcn_global_load_lds((const __attribute__((address_space(1))) char*)g,
                                   (__attribute__((address_space(3))) char*)l, 16, 0, 0);
}

// ---------------- CSR build (scan-free, strided layout) ----------------
__global__ void k_degree(const int* __restrict__ dst, int* __restrict__ cnt, int E) {
  int i = blockIdx.x * blockDim.x + threadIdx.x;
  if (i < E) atomicAdd(&cnt[dst[i]], 1);
}
__global__ void k_invdeg(const int* __restrict__ cnt, float* __restrict__ invdeg, int N) {
  int i = blockIdx.x * blockDim.x + threadIdx.x;
  if (i < N) invdeg[i] = 1.0f / (float)max(cnt[i], 1);
}
__global__ void k_fill(const int* __restrict__ src, const int* __restrict__ dst,
                       int* __restrict__ cnt2, int* __restrict__ csrc, int E, int N) {
  int i = blockIdx.x * blockDim.x + threadIdx.x;
  if (i >= E) return;
  int d = dst[i];
  int r = atomicAdd(&cnt2[d], 1);
  if (r < GCAP) csrc[d + r * N] = src[i];
}

// ---------------- layer 1 (K=16, aggr='add') ----------------
__global__ void k_gatherx(const float* __restrict__ x, const int* __restrict__ cnt,
                          const int* __restrict__ csrc, float* __restrict__ aggx, int N) {
  int t = threadIdx.x;
  int node = blockIdx.x * 16 + (t >> 4);
  int f = t & 15;
  if (node >= N) return;
  int d = min(cnt[node], GCAP);
  float a = 0.f;
  for (int r = 0; r < d; ++r) {
    int s = csrc[node + r * N];
    a += x[(size_t)s * 16 + f];
  }
  aggx[(size_t)node * 16 + f] = a;
}

__global__ __launch_bounds__(512) void k_l1(const float* __restrict__ aggx,
    const float* __restrict__ x, const float* __restrict__ wr1,
    const float* __restrict__ br1, const float* __restrict__ wt1,
    unsigned short* __restrict__ hb, int N) {
  int j = threadIdx.x;                       // output column 0..511
  float wr[16], wt[16];
#pragma unroll
  for (int k = 0; k < 16; ++k) { wr[k] = wr1[k * 512 + j]; wt[k] = wt1[k * 512 + j]; }
  float bj = br1[j];
  __shared__ float sa[16], sx[16];
  for (int n = blockIdx.x; n < N; n += gridDim.x) {
    __syncthreads();
    if (j < 16) sa[j] = aggx[(size_t)n * 16 + j];
    else if (j < 32) sx[j - 16] = x[(size_t)n * 16 + (j - 16)];
    __syncthreads();
    float acc = bj;
#pragma unroll
    for (int k = 0; k < 16; ++k) acc += sa[k] * wr[k] + sx[k] * wt[k];
    hb[(size_t)n * 512 + j] = f2b(fmaxf(acc, 0.f));
  }
}

// ---------------- weight prep: WT[l][n][kf] = bf16(Wfused[kf][n]) ----------------
// kf in [0,512) -> w_rel[l], kf in [512,1024) -> w_root[l]
__global__ void k_prepw(const float* __restrict__ w_rel, const float* __restrict__ w_root,
                        unsigned short* __restrict__ WT) {
  __shared__ float tile[32][33];
  int l = blockIdx.z;
  int kt = blockIdx.y;                       // 0..31 fused-k tile of 32
  int nt = blockIdx.x;                       // 0..15 n tile of 32
  const float* src = (kt < 16 ? w_rel : w_root) + (size_t)l * 512 * 512;
  int kl0 = (kt & 15) * 32;
  int n0 = nt * 32;
  int tx = threadIdx.x, ty = threadIdx.y;    // (32,8)
#pragma unroll
  for (int i = 0; i < 4; ++i)
    tile[ty + i * 8][tx] = src[(size_t)(kl0 + ty + i * 8) * 512 + n0 + tx];
  __syncthreads();
#pragma unroll
  for (int i = 0; i < 4; ++i) {
    int n = n0 + ty + i * 8;
    WT[(size_t)l * 512 * 1024 + (size_t)n * 1024 + kt * 32 + tx] = f2b(tile[tx][ty + i * 8]);
  }
}

// ---------------- mean aggregation: aggb[n] = bf16(mean_{src in N(n)} hb[src]) ----------------
__global__ __launch_bounds__(256) void k_agg(const unsigned short* __restrict__ hb,
    const int* __restrict__ cnt, const int* __restrict__ csrc,
    const float* __restrict__ invdeg, unsigned short* __restrict__ aggb, int N) {
  int node = blockIdx.x * 4 + (threadIdx.x >> 6);   // one wave per node
  int lane = threadIdx.x & 63;
  if (node >= N) return;
  int d = min(cnt[node], GCAP);
  float acc[8] = {0.f, 0.f, 0.f, 0.f, 0.f, 0.f, 0.f, 0.f};
  int col = lane * 8;                               // 8 bf16 = 16B per lane
  for (int r = 0; r < d; ++r) {
    int s = csrc[node + r * N];
    short8 v = *(const short8*)(hb + (size_t)s * 512 + col);
#pragma unroll
    for (int j = 0; j < 8; ++j) acc[j] += b2f((unsigned short)v[j]);
  }
  float idg = invdeg[node];
  short8 o;
#pragma unroll
  for (int j = 0; j < 8; ++j) o[j] = (short)f2b(acc[j] * idg);
  *(short8*)(aggb + (size_t)node * 512 + col) = o;
}

// ---------------- fused GEMM: H = relu([A1|A2][Mpad,1024] @ Wfused + bias) ----------------
// m97 structure: 128x128 tile, BK=32, 4 waves (2x2), 16x16x32 bf16 MFMA
__global__ __launch_bounds__(256) void k_gemm(const unsigned short* __restrict__ A1,
    const unsigned short* __restrict__ A2, const unsigned short* __restrict__ WT,
    const float* __restrict__ bias, unsigned short* __restrict__ Hout) {
  __shared__ unsigned short As[128][32];
  __shared__ unsigned short Bs[128][32];   // Bs[n][k]
  int tid = threadIdx.x;
  int lane = tid & 63, wid = tid >> 6;
  int wm = wid >> 1, wn = wid & 1;
  int m0 = blockIdx.y * 128, n0 = blockIdx.x * 128;
  f32x4 acc[4][4] = {};
  int srow = tid >> 2, skb = (tid & 3) * 8;
  for (int kk = 0; kk < 32; ++kk) {
    int k0 = kk * 32;
    const unsigned short* Ap = (k0 < 512) ? (A1 + k0) : (A2 + (k0 - 512));
    load_lds16(Ap + (size_t)(m0 + srow) * 512 + skb, &As[srow][skb]);
    load_lds16(Ap + (size_t)(m0 + srow + 64) * 512 + skb, &As[srow + 64][skb]);
    load_lds16(WT + (size_t)(n0 + srow) * 1024 + k0 + skb, &Bs[srow][skb]);
    load_lds16(WT + (size_t)(n0 + srow + 64) * 1024 + k0 + skb, &Bs[srow + 64][skb]);
    __syncthreads();
    short8 af[4], bfr[4];
#pragma unroll
    for (int f = 0; f < 4; ++f) {
      af[f]  = *(const short8*)&As[wm * 64 + f * 16 + (lane & 15)][(lane >> 4) * 8];
      bfr[f] = *(const short8*)&Bs[wn * 64 + f * 16 + (lane & 15)][(lane >> 4) * 8];
    }
#pragma unroll
    for (int i = 0; i < 4; ++i)
#pragma unroll
      for (int j = 0; j < 4; ++j)
        acc[i][j] = __builtin_amdgcn_mfma_f32_16x16x32_bf16(af[i], bfr[j], acc[i][j], 0, 0, 0);
    __syncthreads();
  }
#pragma unroll
  for (int i = 0; i < 4; ++i) {
    int rb = m0 + wm * 64 + i * 16 + (lane >> 4) * 4;
#pragma unroll
    for (int j = 0; j < 4; ++j) {
      int c = n0 + wn * 64 + j * 16 + (lane & 15);
      float bv = bias[c];
#pragma unroll
      for (int r = 0; r < 4; ++r) {
        float v = acc[i][j][r] + bv;
        Hout[(size_t)(rb + r) * 512 + c] = f2b(fmaxf(v, 0.f));
      }
    }
  }
}

// ---------------- pooling + output ----------------
__global__ void k_bounds(const int* __restrict__ batch, int* __restrict__ gs,
                         int* __restrict__ ge, int N) {
  int i = blockIdx.x * blockDim.x + threadIdx.x;
  if (i >= N) return;
  int b = batch[i];
  if (i == 0 || batch[i - 1] != b) gs[b] = i;
  if (i == N - 1 || batch[i + 1] != b) ge[b] = i + 1;
}

__global__ __launch_bounds__(128) void k_pool(const unsigned short* __restrict__ hb,
    const int* __restrict__ gs, const int* __restrict__ ge, float* __restrict__ pooled) {
  int g = blockIdx.x, chunk = blockIdx.y, t = threadIdx.x;
  int s = gs[g], e = ge[g];
  float a0 = 0.f, a1 = 0.f, a2 = 0.f, a3 = 0.f;
  for (int n = s + chunk; n < e; n += gridDim.y) {
    short4v v = *(const short4v*)(hb + (size_t)n * 512 + t * 4);
    a0 += b2f((unsigned short)v[0]);
    a1 += b2f((unsigned short)v[1]);
    a2 += b2f((unsigned short)v[2]);
    a3 += b2f((unsigned short)v[3]);
  }
  atomicAdd(&pooled[g * 512 + t * 4 + 0], a0);
  atomicAdd(&pooled[g * 512 + t * 4 + 1], a1);
  atomicAdd(&pooled[g * 512 + t * 4 + 2], a2);
  atomicAdd(&pooled[g * 512 + t * 4 + 3], a3);
}

__global__ void k_out(const float* __restrict__ pooled, const int* __restrict__ gs,
                      const int* __restrict__ ge, const float* __restrict__ w_out,
                      const float* __restrict__ b_out, float* __restrict__ out) {
  int g = blockIdx.x, o = threadIdx.x;
  if (o >= 24) return;
  float inv = 1.0f / (float)max(ge[g] - gs[g], 1);
  float acc = 0.f;
  for (int k = 0; k < 512; ++k) acc += pooled[g * 512 + k] * w_out[k * 24 + o];
  out[g * 24 + o] = acc * inv + b_out[o];
}

extern "C" void kernel_launch(void* const* d_in, const int* in_sizes, int n_in,
                              void* d_out, int out_size, void* d_ws, size_t ws_size,
                              hipStream_t stream) {
  const float* x      = (const float*)d_in[0];
  const int*   ei     = (const int*)d_in[1];
  const int*   batch  = (const int*)d_in[2];
  const float* w_rel1 = (const float*)d_in[3];
  const float* b_rel1 = (const float*)d_in[4];
  const float* w_root1= (const float*)d_in[5];
  const float* w_rel  = (const float*)d_in[6];
  const float* b_rel  = (const float*)d_in[7];
  const float* w_root = (const float*)d_in[8];
  const float* w_out  = (const float*)d_in[9];
  const float* b_out  = (const float*)d_in[10];
  float* out = (float*)d_out;

  int N = in_sizes[2];
  int E = in_sizes[1] / 2;
  int G = out_size / 24;
  const int* esrc = ei;
  const int* edst = ei + E;

  char* ws = (char*)d_ws;
  size_t off = 0;
  auto alloc = [&](size_t b) { void* p = ws + off; off = (off + b + 255) & ~(size_t)255; return p; };
  int*   cnt    = (int*)alloc((size_t)N * 4);
  int*   cnt2   = (int*)alloc((size_t)N * 4);
  float* invdeg = (float*)alloc((size_t)N * 4);
  int*   csrc   = (int*)alloc((size_t)N * GCAP * 4);
  float* aggx   = (float*)alloc((size_t)N * 16 * 4);
  int*   gs     = (int*)alloc((size_t)G * 4);
  int*   ge     = (int*)alloc((size_t)G * 4);
  float* pooled = (float*)alloc((size_t)G * 512 * 4);
  unsigned short* WT   = (unsigned short*)alloc((size_t)6 * 512 * 1024 * 2);
  unsigned short* hb0  = (unsigned short*)alloc((size_t)MPAD * 512 * 2);
  unsigned short* hb1  = (unsigned short*)alloc((size_t)MPAD * 512 * 2);
  unsigned short* aggb = (unsigned short*)alloc((size_t)MPAD * 512 * 2);

  hipMemsetAsync(cnt,  0, (size_t)N * 4, stream);
  hipMemsetAsync(cnt2, 0, (size_t)N * 4, stream);
  hipMemsetAsync(gs,   0, (size_t)G * 4, stream);
  hipMemsetAsync(ge,   0, (size_t)G * 4, stream);
  hipMemsetAsync(pooled, 0, (size_t)G * 512 * 4, stream);
  hipMemsetAsync(hb0  + (size_t)N * 512, 0, (size_t)(MPAD - N) * 512 * 2, stream);
  hipMemsetAsync(aggb + (size_t)N * 512, 0, (size_t)(MPAD - N) * 512 * 2, stream);

  k_degree<<<(E + 255) / 256, 256, 0, stream>>>(edst, cnt, E);
  k_invdeg<<<(N + 255) / 256, 256, 0, stream>>>(cnt, invdeg, N);
  k_fill<<<(E + 255) / 256, 256, 0, stream>>>(esrc, edst, cnt2, csrc, E, N);
  k_prepw<<<dim3(16, 32, 6), dim3(32, 8), 0, stream>>>(w_rel, w_root, WT);
  k_gatherx<<<(N + 15) / 16, 256, 0, stream>>>(x, cnt, csrc, aggx, N);
  k_l1<<<1024, 512, 0, stream>>>(aggx, x, w_rel1, b_rel1, w_root1, hb0, N);

  unsigned short* hin = hb0;
  unsigned short* hout = hb1;
  for (int l = 0; l < 6; ++l) {
    k_agg<<<(N + 3) / 4, 256, 0, stream>>>(hin, cnt, csrc, invdeg, aggb, N);
    k_gemm<<<dim3(4, MPAD / 128), 256, 0, stream>>>(aggb, hin, WT + (size_t)l * 512 * 1024,
                                                    b_rel + (size_t)l * 512, hout);
    unsigned short* t = hin; hin = hout; hout = t;
  }

  k_bounds<<<(N + 255) / 256, 256, 0, stream>>>(batch, gs, ge, N);
  k_pool<<<dim3(G, 8), 128, 0, stream>>>(hin, gs, ge, pooled);
  k_out<<<G, 64, 0, stream>>>(pooled, gs, ge, w_out, b_out, out);
}

// Round 2
// 1356.234 us; speedup vs baseline: 1.0892x; 1.0892x over previous
//
#include <hip/hip_runtime.h>
#include <hip/hip_bf16.h>
#include <stdint.h>

#define GCAP 64          // max stored in-degree (Poisson(16): P(>=64) ~ 1e-20)
#define MPAD 50048       // 391 * 128

typedef __attribute__((ext_vector_type(8))) short short8;
typedef __attribute__((ext_vector_type(4))) short short4v;
typedef __attribute__((ext_vector_type(4))) float f32x4;

__device__ __forceinline__ unsigned short f2b(float f) {
  unsigned u = __float_as_uint(f);
  u += 0x7FFF + ((u >> 16) & 1);            // round-to-nearest-even
  return (unsigned short)(u >> 16);
}
__device__ __forceinline__ float b2f(unsigned short s) {
  return __uint_as_float(((unsigned)s) << 16);
}
__device__ __forceinline__ void load_lds16(const void* g, void* l) {
  __builtin_amdgcn_global_load_lds((const __attribute__((address_space(1))) char*)g,
                                   (__attribute__((address_space(3))) char*)l, 16, 0, 0);
}

// ---------------- CSR build (scan-free, row-major per node) ----------------
__global__ void k_degree(const int* __restrict__ dst, int* __restrict__ cnt, int E) {
  int i = blockIdx.x * blockDim.x + threadIdx.x;
  if (i < E) atomicAdd(&cnt[dst[i]], 1);
}
__global__ void k_invdeg(const int* __restrict__ cnt, float* __restrict__ invdeg, int N) {
  int i = blockIdx.x * blockDim.x + threadIdx.x;
  if (i < N) invdeg[i] = 1.0f / (float)max(cnt[i], 1);
}
__global__ void k_fill(const int* __restrict__ src, const int* __restrict__ dst,
                       int* __restrict__ cnt2, int* __restrict__ csrc, int E, int N) {
  int i = blockIdx.x * blockDim.x + threadIdx.x;
  if (i >= E) return;
  int d = dst[i];
  int r = atomicAdd(&cnt2[d], 1);
  if (r < GCAP) csrc[(size_t)d * GCAP + r] = src[i];
}

// ---------------- layer 1 (K=16, aggr='add') ----------------
__global__ void k_gatherx(const float* __restrict__ x, const int* __restrict__ cnt,
                          const int* __restrict__ csrc, float* __restrict__ aggx, int N) {
  int t = threadIdx.x;
  int node = blockIdx.x * 16 + (t >> 4);
  int f = t & 15;
  if (node >= N) return;
  int d = min(cnt[node], GCAP);
  float a = 0.f;
  for (int r = 0; r < d; ++r) {
    int s = csrc[(size_t)node * GCAP + r];
    a += x[(size_t)s * 16 + f];
  }
  aggx[(size_t)node * 16 + f] = a;
}

__global__ __launch_bounds__(512) void k_l1(const float* __restrict__ aggx,
    const float* __restrict__ x, const float* __restrict__ wr1,
    const float* __restrict__ br1, const float* __restrict__ wt1,
    unsigned short* __restrict__ hb, int N) {
  int j = threadIdx.x;                       // output column 0..511
  float wr[16], wt[16];
#pragma unroll
  for (int k = 0; k < 16; ++k) { wr[k] = wr1[k * 512 + j]; wt[k] = wt1[k * 512 + j]; }
  float bj = br1[j];
  __shared__ float sa[16], sx[16];
  for (int n = blockIdx.x; n < N; n += gridDim.x) {
    __syncthreads();
    if (j < 16) sa[j] = aggx[(size_t)n * 16 + j];
    else if (j < 32) sx[j - 16] = x[(size_t)n * 16 + (j - 16)];
    __syncthreads();
    float acc = bj;
#pragma unroll
    for (int k = 0; k < 16; ++k) acc += sa[k] * wr[k] + sx[k] * wt[k];
    hb[(size_t)n * 512 + j] = f2b(fmaxf(acc, 0.f));
  }
}

// ---------------- weight prep: WT[l][n][kf] = bf16(Wfused[kf][n]) ----------------
__global__ void k_prepw(const float* __restrict__ w_rel, const float* __restrict__ w_root,
                        unsigned short* __restrict__ WT) {
  __shared__ float tile[32][33];
  int l = blockIdx.z;
  int kt = blockIdx.y;                       // 0..31 fused-k tile of 32
  int nt = blockIdx.x;                       // 0..15 n tile of 32
  const float* src = (kt < 16 ? w_rel : w_root) + (size_t)l * 512 * 512;
  int kl0 = (kt & 15) * 32;
  int n0 = nt * 32;
  int tx = threadIdx.x, ty = threadIdx.y;    // (32,8)
#pragma unroll
  for (int i = 0; i < 4; ++i)
    tile[ty + i * 8][tx] = src[(size_t)(kl0 + ty + i * 8) * 512 + n0 + tx];
  __syncthreads();
#pragma unroll
  for (int i = 0; i < 4; ++i) {
    int n = n0 + ty + i * 8;
    WT[(size_t)l * 512 * 1024 + (size_t)n * 1024 + kt * 32 + tx] = f2b(tile[tx][ty + i * 8]);
  }
}

// ---------------- mean aggregation, 8-deep MLP gather ----------------
__global__ __launch_bounds__(256) void k_agg(const unsigned short* __restrict__ hb,
    const int* __restrict__ cnt, const int* __restrict__ csrc,
    const float* __restrict__ invdeg, unsigned short* __restrict__ aggb, int N) {
  int node = blockIdx.x * 4 + (threadIdx.x >> 6);   // one wave per node
  int lane = threadIdx.x & 63;
  if (node >= N) return;
  int d = min(cnt[node], GCAP);
  const int4* idxp = (const int4*)(csrc + (size_t)node * GCAP);
  float acc[8] = {0.f, 0.f, 0.f, 0.f, 0.f, 0.f, 0.f, 0.f};
  int col = lane * 8;                               // 8 bf16 = 16B per lane
  int ng = (d + 7) >> 3;                            // groups of 8 neighbors
  for (int g = 0; g < ng; ++g) {
    int4 i0 = idxp[2 * g];
    int4 i1 = idxp[2 * g + 1];
    int base = g * 8;
    int idx[8] = {i0.x, i0.y, i0.z, i0.w, i1.x, i1.y, i1.z, i1.w};
    short8 v[8];
#pragma unroll
    for (int j = 0; j < 8; ++j) {
      int s = (base + j < d) ? idx[j] : 0;          // masked tail -> hot row 0
      v[j] = *(const short8*)(hb + (size_t)s * 512 + col);
    }
#pragma unroll
    for (int j = 0; j < 8; ++j) {
      float w = (base + j < d) ? 1.0f : 0.0f;
#pragma unroll
      for (int q = 0; q < 8; ++q) acc[q] += w * b2f((unsigned short)v[j][q]);
    }
  }
  float idg = invdeg[node];
  short8 o;
#pragma unroll
  for (int j = 0; j < 8; ++j) o[j] = (short)f2b(acc[j] * idg);
  *(short8*)(aggb + (size_t)node * 512 + col) = o;
}

// ---------------- fused GEMM: H = relu([A1|A2][Mpad,1024] @ Wfused + bias) ----------------
// m97 structure: 128x128 tile, BK=32, 4 waves (2x2), 16x16x32 bf16 MFMA
// 1D grid + chunked bijective XCD swizzle (m204), m-major so the 4 n-tiles of
// one m-tile land on the same XCD L2 (A-panel fetched ~once instead of 4x).
__global__ __launch_bounds__(256) void k_gemm(const unsigned short* __restrict__ A1,
    const unsigned short* __restrict__ A2, const unsigned short* __restrict__ WT,
    const float* __restrict__ bias, unsigned short* __restrict__ Hout, int nwg) {
  int bid = blockIdx.x;
  int q = nwg >> 3, r = nwg & 7;
  int xcd = bid & 7, i0 = bid >> 3;
  int lb = (xcd < r ? xcd * (q + 1) : r * (q + 1) + (xcd - r) * q) + i0;
  int m0 = (lb >> 2) * 128, n0 = (lb & 3) * 128;

  __shared__ unsigned short As[128][32];
  __shared__ unsigned short Bs[128][32];   // Bs[n][k]
  int tid = threadIdx.x;
  int lane = tid & 63, wid = tid >> 6;
  int wm = wid >> 1, wn = wid & 1;
  f32x4 acc[4][4] = {};
  int srow = tid >> 2, skb = (tid & 3) * 8;
  for (int kk = 0; kk < 32; ++kk) {
    int k0 = kk * 32;
    const unsigned short* Ap = (k0 < 512) ? (A1 + k0) : (A2 + (k0 - 512));
    load_lds16(Ap + (size_t)(m0 + srow) * 512 + skb, &As[srow][skb]);
    load_lds16(Ap + (size_t)(m0 + srow + 64) * 512 + skb, &As[srow + 64][skb]);
    load_lds16(WT + (size_t)(n0 + srow) * 1024 + k0 + skb, &Bs[srow][skb]);
    load_lds16(WT + (size_t)(n0 + srow + 64) * 1024 + k0 + skb, &Bs[srow + 64][skb]);
    __syncthreads();
    short8 af[4], bfr[4];
#pragma unroll
    for (int f = 0; f < 4; ++f) {
      af[f]  = *(const short8*)&As[wm * 64 + f * 16 + (lane & 15)][(lane >> 4) * 8];
      bfr[f] = *(const short8*)&Bs[wn * 64 + f * 16 + (lane & 15)][(lane >> 4) * 8];
    }
#pragma unroll
    for (int i = 0; i < 4; ++i)
#pragma unroll
      for (int j = 0; j < 4; ++j)
        acc[i][j] = __builtin_amdgcn_mfma_f32_16x16x32_bf16(af[i], bfr[j], acc[i][j], 0, 0, 0);
    __syncthreads();
  }
#pragma unroll
  for (int i = 0; i < 4; ++i) {
    int rb = m0 + wm * 64 + i * 16 + (lane >> 4) * 4;
#pragma unroll
    for (int j = 0; j < 4; ++j) {
      int c = n0 + wn * 64 + j * 16 + (lane & 15);
      float bv = bias[c];
#pragma unroll
      for (int rr = 0; rr < 4; ++rr) {
        float v = acc[i][j][rr] + bv;
        Hout[(size_t)(rb + rr) * 512 + c] = f2b(fmaxf(v, 0.f));
      }
    }
  }
}

// ---------------- pooling + output ----------------
__global__ void k_bounds(const int* __restrict__ batch, int* __restrict__ gs,
                         int* __restrict__ ge, int N) {
  int i = blockIdx.x * blockDim.x + threadIdx.x;
  if (i >= N) return;
  int b = batch[i];
  if (i == 0 || batch[i - 1] != b) gs[b] = i;
  if (i == N - 1 || batch[i + 1] != b) ge[b] = i + 1;
}

__global__ __launch_bounds__(128) void k_pool(const unsigned short* __restrict__ hb,
    const int* __restrict__ gs, const int* __restrict__ ge, float* __restrict__ pooled) {
  int g = blockIdx.x, chunk = blockIdx.y, t = threadIdx.x;
  int s = gs[g], e = ge[g];
  float a0 = 0.f, a1 = 0.f, a2 = 0.f, a3 = 0.f;
  for (int n = s + chunk; n < e; n += gridDim.y) {
    short4v v = *(const short4v*)(hb + (size_t)n * 512 + t * 4);
    a0 += b2f((unsigned short)v[0]);
    a1 += b2f((unsigned short)v[1]);
    a2 += b2f((unsigned short)v[2]);
    a3 += b2f((unsigned short)v[3]);
  }
  atomicAdd(&pooled[g * 512 + t * 4 + 0], a0);
  atomicAdd(&pooled[g * 512 + t * 4 + 1], a1);
  atomicAdd(&pooled[g * 512 + t * 4 + 2], a2);
  atomicAdd(&pooled[g * 512 + t * 4 + 3], a3);
}

__global__ void k_out(const float* __restrict__ pooled, const int* __restrict__ gs,
                      const int* __restrict__ ge, const float* __restrict__ w_out,
                      const float* __restrict__ b_out, float* __restrict__ out) {
  int g = blockIdx.x, o = threadIdx.x;
  if (o >= 24) return;
  float inv = 1.0f / (float)max(ge[g] - gs[g], 1);
  float acc = 0.f;
  for (int k = 0; k < 512; ++k) acc += pooled[g * 512 + k] * w_out[k * 24 + o];
  out[g * 24 + o] = acc * inv + b_out[o];
}

extern "C" void kernel_launch(void* const* d_in, const int* in_sizes, int n_in,
                              void* d_out, int out_size, void* d_ws, size_t ws_size,
                              hipStream_t stream) {
  const float* x      = (const float*)d_in[0];
  const int*   ei     = (const int*)d_in[1];
  const int*   batch  = (const int*)d_in[2];
  const float* w_rel1 = (const float*)d_in[3];
  const float* b_rel1 = (const float*)d_in[4];
  const float* w_root1= (const float*)d_in[5];
  const float* w_rel  = (const float*)d_in[6];
  const float* b_rel  = (const float*)d_in[7];
  const float* w_root = (const float*)d_in[8];
  const float* w_out  = (const float*)d_in[9];
  const float* b_out  = (const float*)d_in[10];
  float* out = (float*)d_out;

  int N = in_sizes[2];
  int E = in_sizes[1] / 2;
  int G = out_size / 24;
  const int* esrc = ei;
  const int* edst = ei + E;

  char* ws = (char*)d_ws;
  size_t off = 0;
  auto alloc = [&](size_t b) { void* p = ws + off; off = (off + b + 255) & ~(size_t)255; return p; };
  int*   cnt    = (int*)alloc((size_t)N * 4);
  int*   cnt2   = (int*)alloc((size_t)N * 4);
  float* invdeg = (float*)alloc((size_t)N * 4);
  int*   csrc   = (int*)alloc((size_t)N * GCAP * 4);
  float* aggx   = (float*)alloc((size_t)N * 16 * 4);
  int*   gs     = (int*)alloc((size_t)G * 4);
  int*   ge     = (int*)alloc((size_t)G * 4);
  float* pooled = (float*)alloc((size_t)G * 512 * 4);
  unsigned short* WT   = (unsigned short*)alloc((size_t)6 * 512 * 1024 * 2);
  unsigned short* hb0  = (unsigned short*)alloc((size_t)MPAD * 512 * 2);
  unsigned short* hb1  = (unsigned short*)alloc((size_t)MPAD * 512 * 2);
  unsigned short* aggb = (unsigned short*)alloc((size_t)MPAD * 512 * 2);

  hipMemsetAsync(cnt,  0, (size_t)N * 4, stream);
  hipMemsetAsync(cnt2, 0, (size_t)N * 4, stream);
  hipMemsetAsync(gs,   0, (size_t)G * 4, stream);
  hipMemsetAsync(ge,   0, (size_t)G * 4, stream);
  hipMemsetAsync(pooled, 0, (size_t)G * 512 * 4, stream);
  hipMemsetAsync(hb0  + (size_t)N * 512, 0, (size_t)(MPAD - N) * 512 * 2, stream);
  hipMemsetAsync(aggb + (size_t)N * 512, 0, (size_t)(MPAD - N) * 512 * 2, stream);

  k_degree<<<(E + 255) / 256, 256, 0, stream>>>(edst, cnt, E);
  k_invdeg<<<(N + 255) / 256, 256, 0, stream>>>(cnt, invdeg, N);
  k_fill<<<(E + 255) / 256, 256, 0, stream>>>(esrc, edst, cnt2, csrc, E, N);
  k_prepw<<<dim3(16, 32, 6), dim3(32, 8), 0, stream>>>(w_rel, w_root, WT);
  k_gatherx<<<(N + 15) / 16, 256, 0, stream>>>(x, cnt, csrc, aggx, N);
  k_l1<<<1024, 512, 0, stream>>>(aggx, x, w_rel1, b_rel1, w_root1, hb0, N);

  int nwg = (MPAD / 128) * 4;
  unsigned short* hin = hb0;
  unsigned short* hout = hb1;
  for (int l = 0; l < 6; ++l) {
    k_agg<<<(N + 3) / 4, 256, 0, stream>>>(hin, cnt, csrc, invdeg, aggb, N);
    k_gemm<<<nwg, 256, 0, stream>>>(aggb, hin, WT + (size_t)l * 512 * 1024,
                                    b_rel + (size_t)l * 512, hout, nwg);
    unsigned short* t = hin; hin = hout; hout = t;
  }

  k_bounds<<<(N + 255) / 256, 256, 0, stream>>>(batch, gs, ge, N);
  k_pool<<<dim3(G, 8), 128, 0, stream>>>(hin, gs, ge, pooled);
  k_out<<<G, 64, 0, stream>>>(pooled, gs, ge, w_out, b_out, out);
}